// Round 2
// 421.601 us; speedup vs baseline: 1.0006x; 1.0006x over previous
//
#include <hip/hip_runtime.h>
#include <math.h>

#define Sn 4096
#define Dn 64
#define CW 3.834951969714103e-4f   // pi/2/4096

typedef __attribute__((ext_vector_type(8)))  short short8;
typedef __attribute__((ext_vector_type(4)))  float f32x4;
typedef __attribute__((ext_vector_type(16))) float f32x16;

// round-half-up bf16 pack: 2x v_add + 1x v_perm
__device__ __forceinline__ unsigned int pack2(float lo, float hi) {
    unsigned int a = __float_as_uint(lo) + 0x8000u;
    unsigned int b = __float_as_uint(hi) + 0x8000u;
    return __builtin_amdgcn_perm(b, a, 0x07060302u);
}
__device__ __forceinline__ float nneg(float x) {
    return x < 0.f ? __expf(x) : x + 1.f;
}

// ---------------------------------------------------------------------------
// init: zero 4 MiB KV accumulator + detect token_mask storage (int32 vs byte)
// (kernel-based clear: hipMemsetAsync in kernel_launch tripped the harness)
// ---------------------------------------------------------------------------
__global__ __launch_bounds__(256) void k_init(float4* kv4, int* flag,
                                              const unsigned char* mask_raw) {
    int i = blockIdx.x * 256 + threadIdx.x;
    kv4[i] = make_float4(0.f, 0.f, 0.f, 0.f);   // grid sized exactly: 4 MiB
    if (blockIdx.x == 0) {
        __shared__ int s_any;
        if (threadIdx.x == 0) s_any = 0;
        __syncthreads();
        int any = 0;
        int base = threadIdx.x * 16;
        #pragma unroll
        for (int j = 0; j < 16; j++) {
            int idx = base + j;
            if ((idx & 3) && mask_raw[idx]) any = 1;
        }
        if (any) s_any = 1;
        __syncthreads();
        if (threadIdx.x == 0) *flag = s_any ? 0 : 1;
    }
}

// ---------------------------------------------------------------------------
// phase 1: KV[d][e] = sum_s kf(k[s,d])*cos(s)*v[s,e]  (and sin variant)
// LDS-FREE / BARRIER-FREE redesign:
//   grid = 8 splits(512 s) x 128 bh, block = 256 = 4 waves.
//   wave w -> 32x32 output tile (dt = w>>1 d-tile, et = w&1 e-tile).
//   mfma_f32_32x32x16_bf16: lane holds 8 CONSECUTIVE s for fixed column
//   (d for A, e for B) -> direct global dword loads, stride 256B; 32
//   consecutive m-lanes cover full 64B lines (4 lines/instr, 100% util).
//   Register double-buffer, 16 loads in flight across a full iteration.
//   sin/cos: one __sincosf per 16-s step + 2-FMA rotation for j=1..7.
//   blockIdx swizzle: bh = blockIdx&127 -> all 8 splits of a bh share an
//   XCD (stride 128 % 8 == 0) -> KV atomics stay in one L2.
// ---------------------------------------------------------------------------
__global__ __launch_bounds__(256, 4) void k_phase1(const float* __restrict__ kk,
                                                   const float* __restrict__ vv,
                                                   float* __restrict__ kv) {
    const int t    = threadIdx.x;
    const int bh   = blockIdx.x & 127;
    const int sblk = (blockIdx.x >> 7) << 9;   // split * 512
    const int lane = t & 63;
    const int w    = t >> 6;
    const int m    = lane & 31;                // column within 32-tile
    const int sl   = lane >> 5;                // k-slice (8 s each)
    const int dt   = w >> 1;                   // d-tile 0..1
    const int et   = w & 1;                    // e-tile 0..1

    const float* kp = kk + (size_t)bh * (Sn * Dn) + (size_t)(sblk + sl * 8) * Dn + dt * 32 + m;
    const float* vp = vv + (size_t)bh * (Sn * Dn) + (size_t)(sblk + sl * 8) * Dn + et * 32 + m;

    // cos/sin(CW*j), j=0..7 (compile-time constants)
    const float CJT[8] = {1.0f,            0.999999926466f, 0.999999705859f, 0.999999338182f,
                          0.999998823452f, 0.999998161643f, 0.999997352766f, 0.999996396820f};
    const float SJT[8] = {0.0f,            3.83495188e-4f,  7.66989641e-4f,  1.15048534e-3f,
                          1.53398019e-3f,  1.91747478e-3f,  2.30096910e-3f,  2.68446310e-3f};

    f32x16 accC, accS;
    #pragma unroll
    for (int i = 0; i < 16; i++) { accC[i] = 0.f; accS[i] = 0.f; }

    float rk[2][8], rv[2][8];
    #pragma unroll
    for (int j = 0; j < 8; j++) {
        rk[0][j] = kp[j * Dn];
        rv[0][j] = vp[j * Dn];
    }
    const float sb0 = (float)(sblk + sl * 8);

    #pragma unroll 2
    for (int st = 0; st < 32; ++st) {          // 32 steps x 16 s = 512 s
        const int cur = st & 1, nxt = cur ^ 1;
        // prefetch next step (issued before current consume -> full-iter window)
        if (st < 31) {
            const float* kq = kp + (size_t)(st + 1) * (16 * Dn);
            const float* vq = vp + (size_t)(st + 1) * (16 * Dn);
            #pragma unroll
            for (int j = 0; j < 8; j++) {
                rk[nxt][j] = kq[j * Dn];
                rv[nxt][j] = vq[j * Dn];
            }
        }
        float sa, ca;
        __sincosf(CW * (sb0 + (float)(st * 16)), &sa, &ca);
        union { unsigned int u[4]; short8 s; } Ac, As, Bv;
        #pragma unroll
        for (int jj = 0; jj < 4; jj++) {
            const float c0 = ca * CJT[2*jj]     - sa * SJT[2*jj];
            const float s0 = sa * CJT[2*jj]     + ca * SJT[2*jj];
            const float c1 = ca * CJT[2*jj + 1] - sa * SJT[2*jj + 1];
            const float s1 = sa * CJT[2*jj + 1] + ca * SJT[2*jj + 1];
            const float f0 = nneg(rk[cur][2*jj]);
            const float f1 = nneg(rk[cur][2*jj + 1]);
            Ac.u[jj] = pack2(f0 * c0, f1 * c1);
            As.u[jj] = pack2(f0 * s0, f1 * s1);
            Bv.u[jj] = pack2(rv[cur][2*jj], rv[cur][2*jj + 1]);
        }
        accC = __builtin_amdgcn_mfma_f32_32x32x16_bf16(Ac.s, Bv.s, accC, 0, 0, 0);
        accS = __builtin_amdgcn_mfma_f32_32x32x16_bf16(As.s, Bv.s, accS, 0, 0, 0);
    }

    // C layout (32x32): col = lane&31 (=e), row = (r&3) + 8*(r>>2) + 4*(lane>>5)
    float* base = kv + (size_t)bh * 8192;
    const int e = et * 32 + m;
    #pragma unroll
    for (int r = 0; r < 16; ++r) {
        const int d = dt * 32 + (r & 3) + 8 * (r >> 2) + 4 * sl;
        atomicAdd(base +        d * 64 + e, accC[r]);
        atomicAdd(base + 4096 + d * 64 + e, accS[r]);
    }
}

// ---------------------------------------------------------------------------
// phase 2: out[s,e] = (qc[s,:]·KV_c[:,e] + qs[s,:]·KV_s[:,e]) * 0.125
// grid = 8 chunks(512 s) x 128 bh (same-XCD per bh -> KV L2-hot), block=256.
// 8 strips of 64 s per block (amortizes the 128-load B-frag gather).
// Nontemporal stores: out is never re-read, keep L2/L3 for inputs.
// ---------------------------------------------------------------------------
__global__ __launch_bounds__(256) void k_phase2(const float* __restrict__ qq,
                                                const void* __restrict__ mask_raw,
                                                const float* __restrict__ kv,
                                                const int* __restrict__ flag,
                                                float* __restrict__ out) {
    const int t    = threadIdx.x;
    const int bh   = blockIdx.x & 127;
    const int sblk = (blockIdx.x >> 7) << 9;   // chunk * 512
    const int b    = bh >> 4;                  // H = 16
    const int lane = t & 63;
    const int w    = t >> 6;
    const int n    = lane & 15;
    const int q4   = lane >> 4;
    const int iflag = *flag;

    // ---- gather B-frags from KV[d][e] (fp32 -> bf16), L2-hot ----
    const float* kvb = kv + (size_t)bh * 8192;
    short8 Bc[4][2], Bs[4][2];
    #pragma unroll
    for (int et = 0; et < 4; et++) {
        const int e = et * 16 + n;
        #pragma unroll
        for (int ks = 0; ks < 2; ks++) {
            const int d0 = ks * 32 + q4 * 8;
            union { unsigned int u[4]; short8 s; } uc, us;
            #pragma unroll
            for (int jj = 0; jj < 4; jj++) {
                float c0 = kvb[(size_t)(d0 + 2 * jj)     * 64 + e];
                float c1 = kvb[(size_t)(d0 + 2 * jj + 1) * 64 + e];
                float s0 = kvb[4096 + (size_t)(d0 + 2 * jj)     * 64 + e];
                float s1 = kvb[4096 + (size_t)(d0 + 2 * jj + 1) * 64 + e];
                uc.u[jj] = pack2(c0, c1);
                us.u[jj] = pack2(s0, s1);
            }
            Bc[et][ks] = uc.s;
            Bs[et][ks] = us.s;
        }
    }

    const float* qb = qq + (size_t)bh * (Sn * Dn);
    float* ob       = out + (size_t)bh * (Sn * Dn);
    const unsigned char* m8 = (const unsigned char*)mask_raw;
    const int* m32          = (const int*)mask_raw;

    float4 pq[2][4];
    float  pmv[2];
    {   // preload strip 0
        int s_row = sblk + w * 16 + n;
        const float* qp = qb + (size_t)s_row * Dn + q4 * 8;
        pq[0][0] = *(const float4*)(qp);
        pq[0][1] = *(const float4*)(qp + 4);
        pq[0][2] = *(const float4*)(qp + 32);
        pq[0][3] = *(const float4*)(qp + 36);
        pmv[0] = iflag ? (m32[b * Sn + s_row] ? 1.f : 0.f)
                       : (m8 [b * Sn + s_row] ? 1.f : 0.f);
    }

    #pragma unroll 2
    for (int strip = 0; strip < 8; strip++) {
        const int cur = strip & 1, nxt = cur ^ 1;
        const int s_base = sblk + strip * 64 + w * 16;
        const int s_row  = s_base + n;         // A-layout: m = lane&15
        float cs, snv;
        __sincosf(CW * (float)s_row, &snv, &cs);
        cs *= pmv[cur]; snv *= pmv[cur];
        float f[16];
        f[0]  = nneg(pq[cur][0].x); f[1]  = nneg(pq[cur][0].y);
        f[2]  = nneg(pq[cur][0].z); f[3]  = nneg(pq[cur][0].w);
        f[4]  = nneg(pq[cur][1].x); f[5]  = nneg(pq[cur][1].y);
        f[6]  = nneg(pq[cur][1].z); f[7]  = nneg(pq[cur][1].w);
        f[8]  = nneg(pq[cur][2].x); f[9]  = nneg(pq[cur][2].y);
        f[10] = nneg(pq[cur][2].z); f[11] = nneg(pq[cur][2].w);
        f[12] = nneg(pq[cur][3].x); f[13] = nneg(pq[cur][3].y);
        f[14] = nneg(pq[cur][3].z); f[15] = nneg(pq[cur][3].w);
        union { unsigned int u[4]; short8 s; } ac0, as0, ac1, as1;
        #pragma unroll
        for (int j = 0; j < 4; j++) {
            ac0.u[j] = pack2(f[2*j]     * cs,  f[2*j + 1]     * cs);
            as0.u[j] = pack2(f[2*j]     * snv, f[2*j + 1]     * snv);
            ac1.u[j] = pack2(f[8 + 2*j] * cs,  f[8 + 2*j + 1] * cs);
            as1.u[j] = pack2(f[8 + 2*j] * snv, f[8 + 2*j + 1] * snv);
        }
        // ---- prefetch next strip's q + mask (hides under MFMA + stores) ----
        if (strip < 7) {
            int s_row2 = sblk + (strip + 1) * 64 + w * 16 + n;
            const float* qp = qb + (size_t)s_row2 * Dn + q4 * 8;
            pq[nxt][0] = *(const float4*)(qp);
            pq[nxt][1] = *(const float4*)(qp + 4);
            pq[nxt][2] = *(const float4*)(qp + 32);
            pq[nxt][3] = *(const float4*)(qp + 36);
            pmv[nxt] = iflag ? (m32[b * Sn + s_row2] ? 1.f : 0.f)
                             : (m8 [b * Sn + s_row2] ? 1.f : 0.f);
        }
        f32x4 acc[4];
        #pragma unroll
        for (int et = 0; et < 4; et++) acc[et] = (f32x4){0.f, 0.f, 0.f, 0.f};
        #pragma unroll
        for (int et = 0; et < 4; et++) {
            acc[et] = __builtin_amdgcn_mfma_f32_16x16x32_bf16(ac0.s, Bc[et][0], acc[et], 0, 0, 0);
            acc[et] = __builtin_amdgcn_mfma_f32_16x16x32_bf16(ac1.s, Bc[et][1], acc[et], 0, 0, 0);
            acc[et] = __builtin_amdgcn_mfma_f32_16x16x32_bf16(as0.s, Bs[et][0], acc[et], 0, 0, 0);
            acc[et] = __builtin_amdgcn_mfma_f32_16x16x32_bf16(as1.s, Bs[et][1], acc[et], 0, 0, 0);
        }
        // C layout: col = lane&15 (=e), row = quad*4 + reg (=s offset)
        #pragma unroll
        for (int et = 0; et < 4; et++) {
            #pragma unroll
            for (int r = 0; r < 4; r++) {
                int row = q4 * 4 + r;
                __builtin_nontemporal_store(acc[et][r] * 0.125f,
                    ob + (size_t)(s_base + row) * 64 + et * 16 + n);
            }
        }
    }
}

extern "C" void kernel_launch(void* const* d_in, const int* in_sizes, int n_in,
                              void* d_out, int out_size, void* d_ws, size_t ws_size,
                              hipStream_t stream) {
    const float* q = (const float*)d_in[0];
    const float* k = (const float*)d_in[1];
    const float* v = (const float*)d_in[2];
    const void* mask = d_in[3];
    int*   flag = (int*)d_ws;
    float* kv   = (float*)((char*)d_ws + 256);   // 4 MiB KV accumulator

    k_init  <<<1024, 256, 0, stream>>>((float4*)kv, flag, (const unsigned char*)mask);
    k_phase1<<<1024, 256, 0, stream>>>(k, v, kv);
    k_phase2<<<1024, 256, 0, stream>>>(q, mask, kv, flag, (float*)d_out);
}